// Round 1
// baseline (771.542 us; speedup 1.0000x reference)
//
#include <hip/hip_runtime.h>

#define VOCAB 400000
#define DIM   300
#define HID   32
#define NOUT  2
#define BATCH 16384
#define SEQ   50

// K1: one wave (64 lanes) per batch row. Gather 50 emb rows (float4-vectorized,
// rows are 16B-aligned since 1200 % 16 == 0), mean-pool in registers, then
// h = relu(pooled @ V_w^T + V_b) via per-lane partial dots + shfl_xor butterfly,
// then logits = h @ W_w^T + W_b, written to workspace.
__global__ __launch_bounds__(256) void dan_main(
    const int*   __restrict__ tokens,
    const float* __restrict__ emb,
    const float* __restrict__ Vw,
    const float* __restrict__ Vb,
    const float* __restrict__ Ww,
    const float* __restrict__ Wb,
    float*       __restrict__ logits)
{
    const int wave = threadIdx.x >> 6;
    const int lane = threadIdx.x & 63;
    const int row  = blockIdx.x * 4 + wave;
    if (row >= BATCH) return;

    const int* toks = tokens + row * SEQ;

    // DIM = 300 floats = 75 float4. Lane l owns float4 idx l (dims 4l..4l+3)
    // and, for lanes 0..10, float4 idx 64+l (dims 256+4l..259+4l).
    const bool has1 = (lane < (DIM / 4 - 64));  // lanes 0..10

    float4 acc0 = make_float4(0.f, 0.f, 0.f, 0.f);
    float4 acc1 = make_float4(0.f, 0.f, 0.f, 0.f);

    for (int s = 0; s < SEQ; ++s) {
        const int t = toks[s];  // wave-uniform (scalar) load
        const float4* e = (const float4*)(emb + (size_t)t * DIM);
        float4 v0 = e[lane];
        acc0.x += v0.x; acc0.y += v0.y; acc0.z += v0.z; acc0.w += v0.w;
        if (has1) {
            float4 v1 = e[64 + lane];
            acc1.x += v1.x; acc1.y += v1.y; acc1.z += v1.z; acc1.w += v1.w;
        }
    }
    const float inv = 1.0f / (float)SEQ;
    acc0.x *= inv; acc0.y *= inv; acc0.z *= inv; acc0.w *= inv;
    acc1.x *= inv; acc1.y *= inv; acc1.z *= inv; acc1.w *= inv;

    // Per-lane partial dot products for all 32 hidden units.
    float hp[HID];
    #pragma unroll
    for (int k = 0; k < HID; ++k) {
        const float4* vr = (const float4*)(Vw + k * DIM);
        float4 w0 = vr[lane];
        float p = acc0.x * w0.x + acc0.y * w0.y + acc0.z * w0.z + acc0.w * w0.w;
        if (has1) {
            float4 w1 = vr[64 + lane];
            p += acc1.x * w1.x + acc1.y * w1.y + acc1.z * w1.z + acc1.w * w1.w;
        }
        hp[k] = p;
    }

    // Butterfly reduce across the 64-lane wave; afterwards every lane holds
    // the full sums.
    #pragma unroll
    for (int m = 1; m < 64; m <<= 1) {
        #pragma unroll
        for (int k = 0; k < HID; ++k)
            hp[k] += __shfl_xor(hp[k], m, 64);
    }

    float l0 = Wb[0], l1 = Wb[1];
    #pragma unroll
    for (int k = 0; k < HID; ++k) {
        float h = hp[k] + Vb[k];
        h = h > 0.f ? h : 0.f;          // relu
        l0 += h * Ww[k];                // W_w[0][k]
        l1 += h * Ww[HID + k];          // W_w[1][k]
    }
    if (lane == 0) {
        logits[row * 2 + 0] = l0;
        logits[row * 2 + 1] = l1;
    }
}

// K2: single block computes per-column (axis=0) max and log-sum-exp over the
// 16384 rows: c[j] = m_j + log(sum_b exp(logits[b][j] - m_j)).
__global__ __launch_bounds__(1024) void dan_reduce(
    const float* __restrict__ logits, float* __restrict__ c)
{
    __shared__ float r0[1024];
    __shared__ float r1[1024];
    const int tid = threadIdx.x;

    float m0 = -INFINITY, m1 = -INFINITY;
    for (int b = tid; b < BATCH; b += 1024) {
        m0 = fmaxf(m0, logits[b * 2 + 0]);
        m1 = fmaxf(m1, logits[b * 2 + 1]);
    }
    r0[tid] = m0; r1[tid] = m1;
    __syncthreads();
    for (int s = 512; s > 0; s >>= 1) {
        if (tid < s) {
            r0[tid] = fmaxf(r0[tid], r0[tid + s]);
            r1[tid] = fmaxf(r1[tid], r1[tid + s]);
        }
        __syncthreads();
    }
    m0 = r0[0]; m1 = r1[0];
    __syncthreads();

    float s0 = 0.f, s1 = 0.f;
    for (int b = tid; b < BATCH; b += 1024) {
        s0 += __expf(logits[b * 2 + 0] - m0);
        s1 += __expf(logits[b * 2 + 1] - m1);
    }
    r0[tid] = s0; r1[tid] = s1;
    __syncthreads();
    for (int s = 512; s > 0; s >>= 1) {
        if (tid < s) {
            r0[tid] += r0[tid + s];
            r1[tid] += r1[tid + s];
        }
        __syncthreads();
    }
    if (tid == 0) {
        c[0] = m0 + __logf(r0[0]);
        c[1] = m1 + __logf(r1[0]);
    }
}

// K3: out[b][j] = logits[b][j] - c[j]
__global__ __launch_bounds__(256) void dan_final(
    const float* __restrict__ logits, const float* __restrict__ c,
    float* __restrict__ out)
{
    const int idx = blockIdx.x * blockDim.x + threadIdx.x;
    if (idx < BATCH * NOUT)
        out[idx] = logits[idx] - c[idx & 1];
}

extern "C" void kernel_launch(void* const* d_in, const int* in_sizes, int n_in,
                              void* d_out, int out_size, void* d_ws, size_t ws_size,
                              hipStream_t stream) {
    const int*   tokens = (const int*)  d_in[0];
    const float* emb    = (const float*)d_in[1];
    const float* Vw     = (const float*)d_in[2];
    const float* Vb     = (const float*)d_in[3];
    const float* Ww     = (const float*)d_in[4];
    const float* Wb     = (const float*)d_in[5];
    float* out    = (float*)d_out;
    float* logits = (float*)d_ws;                 // BATCH*NOUT floats = 128 KB
    float* c      = logits + BATCH * NOUT;        // 2 floats

    dan_main  <<<BATCH / 4, 256, 0, stream>>>(tokens, emb, Vw, Vb, Ww, Wb, logits);
    dan_reduce<<<1, 1024, 0, stream>>>(logits, c);
    dan_final <<<(BATCH * NOUT + 255) / 256, 256, 0, stream>>>(logits, c, out);
}